// Round 1
// baseline (282030.347 us; speedup 1.0000x reference)
//
#include <hip/hip_runtime.h>
#include <hip/hip_cooperative_groups.h>

namespace cg = cooperative_groups;

#define NODES 1024
#define LAYERS 5
#define SEQ 2048
#define IN_DIM 30
#define OUT_DIM 12
#define SLOPE 0.01f

__device__ __forceinline__ float sigmoidf_(float x) { return 1.0f / (1.0f + expf(-x)); }

// ---------------- FC1: concat(sim,real,act) @ W1^T + b1, leaky ----------------
__global__ __launch_bounds__(256) void fc1_kernel(
    const float* __restrict__ sim, const float* __restrict__ realv,
    const float* __restrict__ act, const float* __restrict__ W1,
    const float* __restrict__ b1, float* __restrict__ x_out)
{
    int t = blockIdx.x;
    __shared__ float in_s[IN_DIM];
    int tid = threadIdx.x;
    if (tid < 12) in_s[tid] = sim[t * 12 + tid];
    else if (tid < 24) in_s[tid] = realv[t * 12 + (tid - 12)];
    else if (tid < 30) in_s[tid] = act[t * 6 + (tid - 24)];
    __syncthreads();
    for (int n = tid; n < NODES; n += 256) {
        float acc = b1[n];
        const float* w = W1 + n * IN_DIM;
        #pragma unroll
        for (int k = 0; k < IN_DIM; ++k) acc += w[k] * in_s[k];
        x_out[t * NODES + n] = acc > 0.f ? acc : SLOPE * acc;
    }
}

// ---------------- xproj: XP = X @ W^T + (b_ih + b_hh) ----------------
// X [SEQ][NODES] row-major, W [4N][NODES] row-major, XP [SEQ][4N]
#define BM 64
#define BN 64
#define BK 16

__global__ __launch_bounds__(256) void xproj_kernel(
    const float* __restrict__ X, const float* __restrict__ W,
    const float* __restrict__ bih, const float* __restrict__ bhh,
    float* __restrict__ XP)
{
    const int GN = 4 * NODES;
    int bm = blockIdx.y;
    int bn = blockIdx.x;
    __shared__ float As[BK][BM];
    __shared__ float Bs[BK][BN];
    int tid = threadIdx.x;
    int tx = tid % 16, ty = tid / 16;
    int arow = tid / 4;
    int acol4 = (tid % 4) * 4;
    float acc[4][4] = {};

    for (int k0 = 0; k0 < NODES; k0 += BK) {
        float4 a = *(const float4*)&X[(size_t)(bm * BM + arow) * NODES + k0 + acol4];
        As[acol4 + 0][arow] = a.x; As[acol4 + 1][arow] = a.y;
        As[acol4 + 2][arow] = a.z; As[acol4 + 3][arow] = a.w;
        float4 b = *(const float4*)&W[(size_t)(bn * BN + arow) * NODES + k0 + acol4];
        Bs[acol4 + 0][arow] = b.x; Bs[acol4 + 1][arow] = b.y;
        Bs[acol4 + 2][arow] = b.z; Bs[acol4 + 3][arow] = b.w;
        __syncthreads();
        #pragma unroll
        for (int k = 0; k < BK; ++k) {
            float ra[4], rb[4];
            #pragma unroll
            for (int m = 0; m < 4; ++m) ra[m] = As[k][ty * 4 + m];
            #pragma unroll
            for (int n = 0; n < 4; ++n) rb[n] = Bs[k][tx * 4 + n];
            #pragma unroll
            for (int m = 0; m < 4; ++m)
                #pragma unroll
                for (int n = 0; n < 4; ++n)
                    acc[m][n] += ra[m] * rb[n];
        }
        __syncthreads();
    }
    #pragma unroll
    for (int m = 0; m < 4; ++m) {
        int t = bm * BM + ty * 4 + m;
        int g0 = bn * BN + tx * 4;
        float4 o;
        o.x = acc[m][0] + bih[g0 + 0] + bhh[g0 + 0];
        o.y = acc[m][1] + bih[g0 + 1] + bhh[g0 + 1];
        o.z = acc[m][2] + bih[g0 + 2] + bhh[g0 + 2];
        o.w = acc[m][3] + bih[g0 + 3] + bhh[g0 + 3];
        *(float4*)&XP[(size_t)t * GN + g0] = o;
    }
}

// ---------------- LSTM recurrence (cooperative, 1 layer) ----------------
// 256 blocks x 256 threads. Block b owns h-indices j = 4b..4b+3 (one per wave).
// W_hh rows {g*N+j : g in 0..3} staged in LDS (16 rows x 4KB = 64KB).
__global__ __launch_bounds__(256) void lstm_recur_kernel(
    const float* __restrict__ Whh,  // [4N][N] this layer
    const float* __restrict__ XP,   // [SEQ][4N] (biases folded)
    const float* __restrict__ h0,   // [N] this layer
    const float* __restrict__ c0,   // [N] this layer
    float* __restrict__ Y)          // [SEQ][N] layer output
{
    cg::grid_group grid = cg::this_grid();
    __shared__ float Wlds[16][NODES];
    int tid = threadIdx.x;
    int wave = tid >> 6;
    int lane = tid & 63;
    int j = blockIdx.x * 4 + wave;

    // stage this wave's 4 rows (gates i,f,g,o for hidden index j)
    #pragma unroll
    for (int g = 0; g < 4; ++g) {
        const float* src = Whh + (size_t)(g * NODES + j) * NODES;
        float* dst = Wlds[wave * 4 + g];
        #pragma unroll
        for (int v = 0; v < 4; ++v) {
            int idx = (lane + v * 64) * 4;
            *(float4*)&dst[idx] = *(const float4*)&src[idx];
        }
    }
    float c = c0[j];
    __syncthreads();

    for (int t = 0; t < SEQ; ++t) {
        const float* hsrc = (t == 0) ? h0 : &Y[(size_t)(t - 1) * NODES];
        float hv[16];
        #pragma unroll
        for (int k = 0; k < 16; ++k) hv[k] = hsrc[lane + k * 64];

        float gate[4];
        #pragma unroll
        for (int g = 0; g < 4; ++g) {
            float acc = 0.f;
            const float* wr = Wlds[wave * 4 + g];
            #pragma unroll
            for (int k = 0; k < 16; ++k) acc += wr[lane + k * 64] * hv[k];
            #pragma unroll
            for (int off = 32; off > 0; off >>= 1) acc += __shfl_xor(acc, off);
            gate[g] = acc + XP[(size_t)t * 4 * NODES + g * NODES + j];
        }
        float ig = sigmoidf_(gate[0]);
        float fg = sigmoidf_(gate[1]);
        float gg = tanhf(gate[2]);
        float og = sigmoidf_(gate[3]);
        c = fg * c + ig * gg;
        float h = og * tanhf(c);
        if (lane == 0) Y[(size_t)t * NODES + j] = h;
        grid.sync();
    }
}

// ---------------- FC2: leaky(Y) @ W2^T + b2 ----------------
__global__ __launch_bounds__(256) void fc2_kernel(
    const float* __restrict__ Y, const float* __restrict__ W2,
    const float* __restrict__ b2, float* __restrict__ out)
{
    int t = blockIdx.x;
    __shared__ float ys[NODES];
    int tid = threadIdx.x;
    for (int n = tid; n < NODES; n += 256) {
        float v = Y[(size_t)t * NODES + n];
        ys[n] = v > 0.f ? v : SLOPE * v;
    }
    __syncthreads();
    int wave = tid >> 6, lane = tid & 63;
    for (int o = wave; o < OUT_DIM; o += 4) {
        float acc = 0.f;
        const float* w = W2 + o * NODES;
        #pragma unroll
        for (int k = 0; k < 16; ++k) acc += w[lane + k * 64] * ys[lane + k * 64];
        #pragma unroll
        for (int off = 32; off > 0; off >>= 1) acc += __shfl_xor(acc, off);
        if (lane == 0) out[t * OUT_DIM + o] = acc + b2[o];
    }
}

extern "C" void kernel_launch(void* const* d_in, const int* in_sizes, int n_in,
                              void* d_out, int out_size, void* d_ws, size_t ws_size,
                              hipStream_t stream) {
    const float* sim  = (const float*)d_in[0];
    const float* relv = (const float*)d_in[1];
    const float* act  = (const float*)d_in[2];
    const float* W1   = (const float*)d_in[3];
    const float* b1   = (const float*)d_in[4];
    const float* W_ih = (const float*)d_in[5];
    const float* W_hh = (const float*)d_in[6];
    const float* b_ih = (const float*)d_in[7];
    const float* b_hh = (const float*)d_in[8];
    const float* W2   = (const float*)d_in[9];
    const float* b2   = (const float*)d_in[10];
    const float* h0   = (const float*)d_in[11];
    const float* c0   = (const float*)d_in[12];
    float* out = (float*)d_out;

    char* ws = (char*)d_ws;
    float* xbuf = (float*)ws;                                  // 8 MB
    float* ybuf = (float*)(ws + (size_t)8 * 1024 * 1024);      // 8 MB
    float* xp   = (float*)(ws + (size_t)16 * 1024 * 1024);     // 32 MB

    fc1_kernel<<<SEQ, 256, 0, stream>>>(sim, relv, act, W1, b1, xbuf);

    float* cur = xbuf;
    float* nxt = ybuf;
    for (int l = 0; l < LAYERS; ++l) {
        const float* Wih_l = W_ih + (size_t)l * 4 * NODES * NODES;
        const float* Whh_l = W_hh + (size_t)l * 4 * NODES * NODES;
        const float* bih_l = b_ih + l * 4 * NODES;
        const float* bhh_l = b_hh + l * 4 * NODES;
        xproj_kernel<<<dim3(4 * NODES / BN, SEQ / BM), 256, 0, stream>>>(
            cur, Wih_l, bih_l, bhh_l, xp);

        const float* h0l = h0 + l * NODES;
        const float* c0l = c0 + l * NODES;
        float* yout = nxt;
        void* args[] = { (void*)&Whh_l, (void*)&xp, (void*)&h0l, (void*)&c0l, (void*)&yout };
        hipLaunchCooperativeKernel((const void*)lstm_recur_kernel,
                                   dim3(256), dim3(256), args, 0, stream);
        float* tmp = cur; cur = nxt; nxt = tmp;
    }

    fc2_kernel<<<SEQ, 256, 0, stream>>>(cur, W2, b2, out);
}

// Round 2
// 126983.093 us; speedup vs baseline: 2.2210x; 2.2210x over previous
//
#include <hip/hip_runtime.h>
#include <hip/hip_cooperative_groups.h>

namespace cg = cooperative_groups;

#define NODES 1024
#define LAYERS 5
#define SEQ 2048
#define IN_DIM 30
#define OUT_DIM 12
#define SLOPE 0.01f
#define NBLK 256

__device__ __forceinline__ float sigmoidf_(float x) { return 1.0f / (1.0f + expf(-x)); }

// ---------------- FC1: concat(sim,real,act) @ W1^T + b1, leaky ----------------
__global__ __launch_bounds__(256) void fc1_kernel(
    const float* __restrict__ sim, const float* __restrict__ realv,
    const float* __restrict__ act, const float* __restrict__ W1,
    const float* __restrict__ b1, float* __restrict__ x_out)
{
    int t = blockIdx.x;
    __shared__ float in_s[IN_DIM];
    int tid = threadIdx.x;
    if (tid < 12) in_s[tid] = sim[t * 12 + tid];
    else if (tid < 24) in_s[tid] = realv[t * 12 + (tid - 12)];
    else if (tid < 30) in_s[tid] = act[t * 6 + (tid - 24)];
    __syncthreads();
    for (int n = tid; n < NODES; n += 256) {
        float acc = b1[n];
        const float* w = W1 + n * IN_DIM;
        #pragma unroll
        for (int k = 0; k < IN_DIM; ++k) acc += w[k] * in_s[k];
        x_out[t * NODES + n] = acc > 0.f ? acc : SLOPE * acc;
    }
}

// ---------------- xproj: XP = X @ W^T + (b_ih + b_hh) ----------------
#define BM 64
#define BN 64
#define BK 16

__global__ __launch_bounds__(256) void xproj_kernel(
    const float* __restrict__ X, const float* __restrict__ W,
    const float* __restrict__ bih, const float* __restrict__ bhh,
    float* __restrict__ XP)
{
    const int GN = 4 * NODES;
    int bm = blockIdx.y;
    int bn = blockIdx.x;
    __shared__ float As[BK][BM];
    __shared__ float Bs[BK][BN];
    int tid = threadIdx.x;
    int tx = tid % 16, ty = tid / 16;
    int arow = tid / 4;
    int acol4 = (tid % 4) * 4;
    float acc[4][4] = {};

    for (int k0 = 0; k0 < NODES; k0 += BK) {
        float4 a = *(const float4*)&X[(size_t)(bm * BM + arow) * NODES + k0 + acol4];
        As[acol4 + 0][arow] = a.x; As[acol4 + 1][arow] = a.y;
        As[acol4 + 2][arow] = a.z; As[acol4 + 3][arow] = a.w;
        float4 b = *(const float4*)&W[(size_t)(bn * BN + arow) * NODES + k0 + acol4];
        Bs[acol4 + 0][arow] = b.x; Bs[acol4 + 1][arow] = b.y;
        Bs[acol4 + 2][arow] = b.z; Bs[acol4 + 3][arow] = b.w;
        __syncthreads();
        #pragma unroll
        for (int k = 0; k < BK; ++k) {
            float ra[4], rb[4];
            #pragma unroll
            for (int m = 0; m < 4; ++m) ra[m] = As[k][ty * 4 + m];
            #pragma unroll
            for (int n = 0; n < 4; ++n) rb[n] = Bs[k][tx * 4 + n];
            #pragma unroll
            for (int m = 0; m < 4; ++m)
                #pragma unroll
                for (int n = 0; n < 4; ++n)
                    acc[m][n] += ra[m] * rb[n];
        }
        __syncthreads();
    }
    #pragma unroll
    for (int m = 0; m < 4; ++m) {
        int t = bm * BM + ty * 4 + m;
        int g0 = bn * BN + tx * 4;
        float4 o;
        o.x = acc[m][0] + bih[g0 + 0] + bhh[g0 + 0];
        o.y = acc[m][1] + bih[g0 + 1] + bhh[g0 + 1];
        o.z = acc[m][2] + bih[g0 + 2] + bhh[g0 + 2];
        o.w = acc[m][3] + bih[g0 + 3] + bhh[g0 + 3];
        *(float4*)&XP[(size_t)t * GN + g0] = o;
    }
}

// ---------------- LSTM recurrence (cooperative launch, hand-rolled barrier) ----------------
// 256 blocks x 256 threads. Block b owns h-indices j = 4b..4b+3 (one per wave).
// Barrier: monotonic counter in d_ws; leader atomicAdd(release) + acquire-spin.
__global__ __launch_bounds__(256) void lstm_recur_kernel(
    const float* __restrict__ Whh,  // [4N][N] this layer
    const float* __restrict__ XP,   // [SEQ][4N] (biases folded)
    const float* __restrict__ h0,   // [N] this layer
    const float* __restrict__ c0,   // [N] this layer
    float* __restrict__ Y,          // [SEQ][N] layer output
    int* __restrict__ cnt)          // barrier counter (zeroed before dispatch)
{
    __shared__ float Wlds[16][NODES];
    int tid = threadIdx.x;
    int wave = tid >> 6;
    int lane = tid & 63;
    int j = blockIdx.x * 4 + wave;

    // stage this wave's 4 rows (gates i,f,g,o for hidden index j)
    #pragma unroll
    for (int g = 0; g < 4; ++g) {
        const float* src = Whh + (size_t)(g * NODES + j) * NODES;
        float* dst = Wlds[wave * 4 + g];
        #pragma unroll
        for (int v = 0; v < 4; ++v) {
            int idx = (lane + v * 64) * 4;
            *(float4*)&dst[idx] = *(const float4*)&src[idx];
        }
    }
    float c = c0[j];
    __syncthreads();

    // prefetch XP for t=0
    float xpg[4];
    #pragma unroll
    for (int g = 0; g < 4; ++g) xpg[g] = XP[(size_t)0 * 4 * NODES + g * NODES + j];

    for (int t = 0; t < SEQ; ++t) {
        const float* hsrc = (t == 0) ? h0 : &Y[(size_t)(t - 1) * NODES];
        float hv[16];
        #pragma unroll
        for (int k = 0; k < 16; ++k) hv[k] = hsrc[lane + k * 64];

        float gate[4];
        #pragma unroll
        for (int g = 0; g < 4; ++g) {
            float acc = 0.f;
            const float* wr = Wlds[wave * 4 + g];
            #pragma unroll
            for (int k = 0; k < 16; ++k) acc += wr[lane + k * 64] * hv[k];
            #pragma unroll
            for (int off = 32; off > 0; off >>= 1) acc += __shfl_xor(acc, off);
            gate[g] = acc + xpg[g];
        }
        float ig = sigmoidf_(gate[0]);
        float fg = sigmoidf_(gate[1]);
        float gg = tanhf(gate[2]);
        float og = sigmoidf_(gate[3]);
        c = fg * c + ig * gg;
        float h = og * tanhf(c);
        if (lane == 0) Y[(size_t)t * NODES + j] = h;

        // prefetch XP for next step (overlaps barrier latency)
        int tn = (t + 1 < SEQ) ? (t + 1) : t;
        #pragma unroll
        for (int g = 0; g < 4; ++g) xpg[g] = XP[(size_t)tn * 4 * NODES + g * NODES + j];

        // hand-rolled grid barrier (monotonic phase counter)
        __syncthreads();
        if (tid == 0) {
            __hip_atomic_fetch_add(cnt, 1, __ATOMIC_RELEASE, __HIP_MEMORY_SCOPE_AGENT);
            int target = (t + 1) * NBLK;
            while (__hip_atomic_load(cnt, __ATOMIC_ACQUIRE, __HIP_MEMORY_SCOPE_AGENT) < target) {}
        }
        __syncthreads();
    }
}

// ---------------- FC2: leaky(Y) @ W2^T + b2 ----------------
__global__ __launch_bounds__(256) void fc2_kernel(
    const float* __restrict__ Y, const float* __restrict__ W2,
    const float* __restrict__ b2, float* __restrict__ out)
{
    int t = blockIdx.x;
    __shared__ float ys[NODES];
    int tid = threadIdx.x;
    for (int n = tid; n < NODES; n += 256) {
        float v = Y[(size_t)t * NODES + n];
        ys[n] = v > 0.f ? v : SLOPE * v;
    }
    __syncthreads();
    int wave = tid >> 6, lane = tid & 63;
    for (int o = wave; o < OUT_DIM; o += 4) {
        float acc = 0.f;
        const float* w = W2 + o * NODES;
        #pragma unroll
        for (int k = 0; k < 16; ++k) acc += w[lane + k * 64] * ys[lane + k * 64];
        #pragma unroll
        for (int off = 32; off > 0; off >>= 1) acc += __shfl_xor(acc, off);
        if (lane == 0) out[t * OUT_DIM + o] = acc + b2[o];
    }
}

extern "C" void kernel_launch(void* const* d_in, const int* in_sizes, int n_in,
                              void* d_out, int out_size, void* d_ws, size_t ws_size,
                              hipStream_t stream) {
    const float* sim  = (const float*)d_in[0];
    const float* relv = (const float*)d_in[1];
    const float* act  = (const float*)d_in[2];
    const float* W1   = (const float*)d_in[3];
    const float* b1   = (const float*)d_in[4];
    const float* W_ih = (const float*)d_in[5];
    const float* W_hh = (const float*)d_in[6];
    const float* b_ih = (const float*)d_in[7];
    const float* b_hh = (const float*)d_in[8];
    const float* W2   = (const float*)d_in[9];
    const float* b2   = (const float*)d_in[10];
    const float* h0   = (const float*)d_in[11];
    const float* c0   = (const float*)d_in[12];
    float* out = (float*)d_out;

    char* ws = (char*)d_ws;
    float* xbuf = (float*)ws;                                  // 8 MB
    float* ybuf = (float*)(ws + (size_t)8 * 1024 * 1024);      // 8 MB
    float* xp   = (float*)(ws + (size_t)16 * 1024 * 1024);     // 32 MB
    char*  cntb = ws + (size_t)48 * 1024 * 1024;               // barrier counters

    // zero the 5 barrier counters (one per layer, separate cache lines)
    hipMemsetAsync(cntb, 0, LAYERS * 128, stream);

    fc1_kernel<<<SEQ, 256, 0, stream>>>(sim, relv, act, W1, b1, xbuf);

    float* cur = xbuf;
    float* nxt = ybuf;
    for (int l = 0; l < LAYERS; ++l) {
        const float* Wih_l = W_ih + (size_t)l * 4 * NODES * NODES;
        const float* Whh_l = W_hh + (size_t)l * 4 * NODES * NODES;
        const float* bih_l = b_ih + l * 4 * NODES;
        const float* bhh_l = b_hh + l * 4 * NODES;
        xproj_kernel<<<dim3(4 * NODES / BN, SEQ / BM), 256, 0, stream>>>(
            cur, Wih_l, bih_l, bhh_l, xp);

        const float* h0l = h0 + l * NODES;
        const float* c0l = c0 + l * NODES;
        float* yout = nxt;
        int* cnt_l = (int*)(cntb + (size_t)l * 128);
        void* args[] = { (void*)&Whh_l, (void*)&xp, (void*)&h0l, (void*)&c0l,
                         (void*)&yout, (void*)&cnt_l };
        hipLaunchCooperativeKernel((const void*)lstm_recur_kernel,
                                   dim3(NBLK), dim3(256), args, 0, stream);
        float* tmp = cur; cur = nxt; nxt = tmp;
    }

    fc2_kernel<<<SEQ, 256, 0, stream>>>(cur, W2, b2, out);
}

// Round 3
// 61293.463 us; speedup vs baseline: 4.6013x; 2.0717x over previous
//
#include <hip/hip_runtime.h>

#define NODES 1024
#define LAYERS 5
#define SEQ 2048
#define IN_DIM 30
#define OUT_DIM 12
#define SLOPE 0.01f
#define NBLK 256

typedef unsigned long long u64;

__device__ __forceinline__ float sigmoidf_(float x) { return 1.0f / (1.0f + expf(-x)); }

// ---------------- FC1: concat(sim,real,act) @ W1^T + b1, leaky ----------------
__global__ __launch_bounds__(256) void fc1_kernel(
    const float* __restrict__ sim, const float* __restrict__ realv,
    const float* __restrict__ act, const float* __restrict__ W1,
    const float* __restrict__ b1, float* __restrict__ x_out)
{
    int t = blockIdx.x;
    __shared__ float in_s[IN_DIM];
    int tid = threadIdx.x;
    if (tid < 12) in_s[tid] = sim[t * 12 + tid];
    else if (tid < 24) in_s[tid] = realv[t * 12 + (tid - 12)];
    else if (tid < 30) in_s[tid] = act[t * 6 + (tid - 24)];
    __syncthreads();
    for (int n = tid; n < NODES; n += 256) {
        float acc = b1[n];
        const float* w = W1 + n * IN_DIM;
        #pragma unroll
        for (int k = 0; k < IN_DIM; ++k) acc += w[k] * in_s[k];
        x_out[t * NODES + n] = acc > 0.f ? acc : SLOPE * acc;
    }
}

// ---------------- xproj: XP = X @ W^T + (b_ih + b_hh) ----------------
#define BM 64
#define BN 64
#define BK 16

__global__ __launch_bounds__(256) void xproj_kernel(
    const float* __restrict__ X, const float* __restrict__ W,
    const float* __restrict__ bih, const float* __restrict__ bhh,
    float* __restrict__ XP)
{
    const int GN = 4 * NODES;
    int bm = blockIdx.y;
    int bn = blockIdx.x;
    __shared__ float As[BK][BM];
    __shared__ float Bs[BK][BN];
    int tid = threadIdx.x;
    int tx = tid % 16, ty = tid / 16;
    int arow = tid / 4;
    int acol4 = (tid % 4) * 4;
    float acc[4][4] = {};

    for (int k0 = 0; k0 < NODES; k0 += BK) {
        float4 a = *(const float4*)&X[(size_t)(bm * BM + arow) * NODES + k0 + acol4];
        As[acol4 + 0][arow] = a.x; As[acol4 + 1][arow] = a.y;
        As[acol4 + 2][arow] = a.z; As[acol4 + 3][arow] = a.w;
        float4 b = *(const float4*)&W[(size_t)(bn * BN + arow) * NODES + k0 + acol4];
        Bs[acol4 + 0][arow] = b.x; Bs[acol4 + 1][arow] = b.y;
        Bs[acol4 + 2][arow] = b.z; Bs[acol4 + 3][arow] = b.w;
        __syncthreads();
        #pragma unroll
        for (int k = 0; k < BK; ++k) {
            float ra[4], rb[4];
            #pragma unroll
            for (int m = 0; m < 4; ++m) ra[m] = As[k][ty * 4 + m];
            #pragma unroll
            for (int n = 0; n < 4; ++n) rb[n] = Bs[k][tx * 4 + n];
            #pragma unroll
            for (int m = 0; m < 4; ++m)
                #pragma unroll
                for (int n = 0; n < 4; ++n)
                    acc[m][n] += ra[m] * rb[n];
        }
        __syncthreads();
    }
    #pragma unroll
    for (int m = 0; m < 4; ++m) {
        int t = bm * BM + ty * 4 + m;
        int g0 = bn * BN + tx * 4;
        float4 o;
        o.x = acc[m][0] + bih[g0 + 0] + bhh[g0 + 0];
        o.y = acc[m][1] + bih[g0 + 1] + bhh[g0 + 1];
        o.z = acc[m][2] + bih[g0 + 2] + bhh[g0 + 2];
        o.w = acc[m][3] + bih[g0 + 3] + bhh[g0 + 3];
        *(float4*)&XP[(size_t)t * GN + g0] = o;
    }
}

// ---------------- LSTM recurrence: flow-sync via packed {flag,h} slots ----------------
// 256 blocks x 256 threads; wave w of block b owns h-index j = 4b + w.
// Publish: one relaxed 8B atomic store {flag=t+1 | bits(h)} to slots[(t+1)&1][j].
// Consume: spin with 16 parallel relaxed 8B loads/lane; h rides with the flag,
// so no fences and no RMW anywhere. Parity double-buffer; max producer lead = 1 step.
__global__ __launch_bounds__(256) void lstm_recur_kernel(
    const float* __restrict__ Whh,  // [4N][N] this layer
    const float* __restrict__ XP,   // [SEQ][4N] (biases folded)
    const float* __restrict__ h0,   // [N] this layer
    const float* __restrict__ c0,   // [N] this layer
    float* __restrict__ Y,          // [SEQ][N] layer output
    u64* __restrict__ slots)        // [2][NODES], zeroed before dispatch
{
    __shared__ float Wlds[16][NODES];
    int tid = threadIdx.x;
    int wave = tid >> 6;
    int lane = tid & 63;
    int j = blockIdx.x * 4 + wave;

    // stage this wave's 4 gate rows (i,f,g,o for hidden index j)
    #pragma unroll
    for (int g = 0; g < 4; ++g) {
        const float* src = Whh + (size_t)(g * NODES + j) * NODES;
        float* dst = Wlds[wave * 4 + g];
        #pragma unroll
        for (int v = 0; v < 4; ++v) {
            int idx = (lane + v * 64) * 4;
            *(float4*)&dst[idx] = *(const float4*)&src[idx];
        }
    }
    float c = c0[j];
    __syncthreads();

    // prefetch XP for t=0
    float xpg[4];
    #pragma unroll
    for (int g = 0; g < 4; ++g) xpg[g] = XP[(size_t)0 * 4 * NODES + g * NODES + j];

    for (int t = 0; t < SEQ; ++t) {
        float hv[16];
        if (t == 0) {
            #pragma unroll
            for (int k = 0; k < 16; ++k) hv[k] = h0[lane + k * 64];
        } else {
            const u64* sl = slots + (size_t)(t & 1) * NODES;
            u64 v[16];
            bool ok = false;
            while (!ok) {
                #pragma unroll
                for (int k = 0; k < 16; ++k)
                    v[k] = __hip_atomic_load(&sl[lane + k * 64],
                                             __ATOMIC_RELAXED, __HIP_MEMORY_SCOPE_AGENT);
                ok = true;
                #pragma unroll
                for (int k = 0; k < 16; ++k)
                    ok = ok && ((int)(v[k] >> 32) == t);
            }
            #pragma unroll
            for (int k = 0; k < 16; ++k) hv[k] = __uint_as_float((unsigned)v[k]);
        }

        float gate[4];
        #pragma unroll
        for (int g = 0; g < 4; ++g) {
            float acc = 0.f;
            const float* wr = Wlds[wave * 4 + g];
            #pragma unroll
            for (int k = 0; k < 16; ++k) acc += wr[lane + k * 64] * hv[k];
            #pragma unroll
            for (int off = 32; off > 0; off >>= 1) acc += __shfl_xor(acc, off);
            gate[g] = acc + xpg[g];
        }
        float ig = sigmoidf_(gate[0]);
        float fg = sigmoidf_(gate[1]);
        float gg = tanhf(gate[2]);
        float og = sigmoidf_(gate[3]);
        c = fg * c + ig * gg;
        float h = og * tanhf(c);

        if (lane == 0) {
            u64 pv = ((u64)(unsigned)(t + 1) << 32) | (u64)__float_as_uint(h);
            __hip_atomic_store(&slots[(size_t)((t + 1) & 1) * NODES + j], pv,
                               __ATOMIC_RELAXED, __HIP_MEMORY_SCOPE_AGENT);
            Y[(size_t)t * NODES + j] = h;  // consumed only by later dispatches
        }

        // prefetch XP for next step (off critical path)
        int tn = (t + 1 < SEQ) ? (t + 1) : t;
        #pragma unroll
        for (int g = 0; g < 4; ++g) xpg[g] = XP[(size_t)tn * 4 * NODES + g * NODES + j];
    }
}

// ---------------- FC2: leaky(Y) @ W2^T + b2 ----------------
__global__ __launch_bounds__(256) void fc2_kernel(
    const float* __restrict__ Y, const float* __restrict__ W2,
    const float* __restrict__ b2, float* __restrict__ out)
{
    int t = blockIdx.x;
    __shared__ float ys[NODES];
    int tid = threadIdx.x;
    for (int n = tid; n < NODES; n += 256) {
        float v = Y[(size_t)t * NODES + n];
        ys[n] = v > 0.f ? v : SLOPE * v;
    }
    __syncthreads();
    int wave = tid >> 6, lane = tid & 63;
    for (int o = wave; o < OUT_DIM; o += 4) {
        float acc = 0.f;
        const float* w = W2 + o * NODES;
        #pragma unroll
        for (int k = 0; k < 16; ++k) acc += w[lane + k * 64] * ys[lane + k * 64];
        #pragma unroll
        for (int off = 32; off > 0; off >>= 1) acc += __shfl_xor(acc, off);
        if (lane == 0) out[t * OUT_DIM + o] = acc + b2[o];
    }
}

extern "C" void kernel_launch(void* const* d_in, const int* in_sizes, int n_in,
                              void* d_out, int out_size, void* d_ws, size_t ws_size,
                              hipStream_t stream) {
    const float* sim  = (const float*)d_in[0];
    const float* relv = (const float*)d_in[1];
    const float* act  = (const float*)d_in[2];
    const float* W1   = (const float*)d_in[3];
    const float* b1   = (const float*)d_in[4];
    const float* W_ih = (const float*)d_in[5];
    const float* W_hh = (const float*)d_in[6];
    const float* b_ih = (const float*)d_in[7];
    const float* b_hh = (const float*)d_in[8];
    const float* W2   = (const float*)d_in[9];
    const float* b2   = (const float*)d_in[10];
    const float* h0   = (const float*)d_in[11];
    const float* c0   = (const float*)d_in[12];
    float* out = (float*)d_out;

    char* ws = (char*)d_ws;
    float* xbuf = (float*)ws;                                  // 8 MB
    float* ybuf = (float*)(ws + (size_t)8 * 1024 * 1024);      // 8 MB
    float* xp   = (float*)(ws + (size_t)16 * 1024 * 1024);     // 32 MB
    char*  slotb = ws + (size_t)48 * 1024 * 1024;              // 5 x 16 KB slot arrays

    // zero all slot arrays (in-graph, every replay -> no stale flags)
    hipMemsetAsync(slotb, 0, LAYERS * 2 * NODES * sizeof(u64), stream);

    fc1_kernel<<<SEQ, 256, 0, stream>>>(sim, relv, act, W1, b1, xbuf);

    float* cur = xbuf;
    float* nxt = ybuf;
    for (int l = 0; l < LAYERS; ++l) {
        const float* Wih_l = W_ih + (size_t)l * 4 * NODES * NODES;
        const float* Whh_l = W_hh + (size_t)l * 4 * NODES * NODES;
        const float* bih_l = b_ih + l * 4 * NODES;
        const float* bhh_l = b_hh + l * 4 * NODES;
        xproj_kernel<<<dim3(4 * NODES / BN, SEQ / BM), 256, 0, stream>>>(
            cur, Wih_l, bih_l, bhh_l, xp);

        const float* h0l = h0 + l * NODES;
        const float* c0l = c0 + l * NODES;
        float* yout = nxt;
        u64* slots_l = (u64*)(slotb + (size_t)l * 2 * NODES * sizeof(u64));
        void* args[] = { (void*)&Whh_l, (void*)&xp, (void*)&h0l, (void*)&c0l,
                         (void*)&yout, (void*)&slots_l };
        hipLaunchCooperativeKernel((const void*)lstm_recur_kernel,
                                   dim3(NBLK), dim3(256), args, 0, stream);
        float* tmp = cur; cur = nxt; nxt = tmp;
    }

    fc2_kernel<<<SEQ, 256, 0, stream>>>(cur, W2, b2, out);
}

// Round 6
// 36467.825 us; speedup vs baseline: 7.7337x; 1.6808x over previous
//
#include <hip/hip_runtime.h>

#define NODES 1024
#define LAYERS 5
#define SEQ 2048
#define IN_DIM 30
#define OUT_DIM 12
#define SLOPE 0.01f
#define RING_D 16

typedef unsigned long long u64;

__device__ __forceinline__ float sigmoidf_(float x) { return 1.0f / (1.0f + expf(-x)); }

// ---------------- FC1: concat(sim,real,act) @ W1^T + b1, leaky ----------------
__global__ __launch_bounds__(256) void fc1_kernel(
    const float* __restrict__ sim, const float* __restrict__ realv,
    const float* __restrict__ act, const float* __restrict__ W1,
    const float* __restrict__ b1, float* __restrict__ x_out)
{
    int t = blockIdx.x;
    __shared__ float in_s[IN_DIM];
    int tid = threadIdx.x;
    if (tid < 12) in_s[tid] = sim[t * 12 + tid];
    else if (tid < 24) in_s[tid] = realv[t * 12 + (tid - 12)];
    else if (tid < 30) in_s[tid] = act[t * 6 + (tid - 24)];
    __syncthreads();
    for (int n = tid; n < NODES; n += 256) {
        float acc = b1[n];
        const float* w = W1 + n * IN_DIM;
        #pragma unroll
        for (int k = 0; k < IN_DIM; ++k) acc += w[k] * in_s[k];
        x_out[t * NODES + n] = acc > 0.f ? acc : SLOPE * acc;
    }
}

// ---------------- xproj: XP = X @ W^T + (b_ih + b_hh) ----------------
#define BM 64
#define BN 64
#define BK 16

__global__ __launch_bounds__(256) void xproj_kernel(
    const float* __restrict__ X, const float* __restrict__ W,
    const float* __restrict__ bih, const float* __restrict__ bhh,
    float* __restrict__ XP)
{
    const int GN = 4 * NODES;
    int bm = blockIdx.y;
    int bn = blockIdx.x;
    __shared__ float As[BK][BM];
    __shared__ float Bs[BK][BN];
    int tid = threadIdx.x;
    int tx = tid % 16, ty = tid / 16;
    int arow = tid / 4;
    int acol4 = (tid % 4) * 4;
    float acc[4][4] = {};

    for (int k0 = 0; k0 < NODES; k0 += BK) {
        float4 a = *(const float4*)&X[(size_t)(bm * BM + arow) * NODES + k0 + acol4];
        As[acol4 + 0][arow] = a.x; As[acol4 + 1][arow] = a.y;
        As[acol4 + 2][arow] = a.z; As[acol4 + 3][arow] = a.w;
        float4 b = *(const float4*)&W[(size_t)(bn * BN + arow) * NODES + k0 + acol4];
        Bs[acol4 + 0][arow] = b.x; Bs[acol4 + 1][arow] = b.y;
        Bs[acol4 + 2][arow] = b.z; Bs[acol4 + 3][arow] = b.w;
        __syncthreads();
        #pragma unroll
        for (int k = 0; k < BK; ++k) {
            float ra[4], rb[4];
            #pragma unroll
            for (int m = 0; m < 4; ++m) ra[m] = As[k][ty * 4 + m];
            #pragma unroll
            for (int n = 0; n < 4; ++n) rb[n] = Bs[k][tx * 4 + n];
            #pragma unroll
            for (int m = 0; m < 4; ++m)
                #pragma unroll
                for (int n = 0; n < 4; ++n)
                    acc[m][n] += ra[m] * rb[n];
        }
        __syncthreads();
    }
    #pragma unroll
    for (int m = 0; m < 4; ++m) {
        int t = bm * BM + ty * 4 + m;
        int g0 = bn * BN + tx * 4;
        float4 o;
        o.x = acc[m][0] + bih[g0 + 0] + bhh[g0 + 0];
        o.y = acc[m][1] + bih[g0 + 1] + bhh[g0 + 1];
        o.z = acc[m][2] + bih[g0 + 2] + bhh[g0 + 2];
        o.w = acc[m][3] + bih[g0 + 3] + bhh[g0 + 3];
        *(float4*)&XP[(size_t)t * GN + g0] = o;
    }
}

// ---------------- Fused LSTM group (NL=1 or 2 layers), wavefront pipeline ----------------
// 256 blocks (cooperative max that validates on this runtime) x (NL*256) threads.
// Wave w of a block: group-layer lg = w>>2, unit j = blockIdx.x*4 + (w&3);
// global layer l = l_base + lg. First group-layer consumes precomputed
// XP[SEQ][4N] (biases folded; only W_hh in regs, 64 VGPR); second also holds
// 4 W_ih rows (128 VGPR) and consumes the prev layer's ring on the fly.
// Rings: rings[l][RING_D][NODES] of packed {flag=t+1, h} u64; relaxed 8B agent
// atomics only (payload rides with the flag; the publish store is data-dependent
// on every gathered word, so no fences / no RMW are needed).
// Consumer at step t: own flags == t (slot t%D); prev flags == t+1 (slot (t+1)%D).
// Producer throttle (non-last layer, t>=D): downstream unit j's published flag
// >= t+2-D before overwriting slot (t+1)%D. Own-layer lead bound is 1 << D.
__global__ __launch_bounds__(512, 2) void lstm_group_kernel(
    const float* __restrict__ Wih,   // [L][4N][N] (global base)
    const float* __restrict__ Whh,   // [L][4N][N] (global base)
    const float* __restrict__ bih,   // [L][4N]
    const float* __restrict__ bhh,   // [L][4N]
    const float* __restrict__ XP,    // [SEQ][4N] first-group-layer input proj
    const float* __restrict__ h0,    // [L][N]
    const float* __restrict__ c0,    // [L][N]
    float* __restrict__ Yout,        // [SEQ][N] last-group-layer output
    u64* rings, int l_base, int NL)
{
    int tid = threadIdx.x;
    int wave = tid >> 6, lane = tid & 63;
    int lg = wave >> 2;                    // 0..NL-1
    int j = blockIdx.x * 4 + (wave & 3);   // 0..1023
    int l = l_base + lg;
    bool first = (lg == 0);
    bool last  = (lg == NL - 1);

    // ---- stage weights into registers ----
    float whh[4][16];
    {
        const float* wp = Whh + (size_t)l * 4 * NODES * NODES;
        #pragma unroll
        for (int g = 0; g < 4; ++g)
            #pragma unroll
            for (int k = 0; k < 16; ++k)
                whh[g][k] = wp[(size_t)(g * NODES + j) * NODES + lane + k * 64];
    }
    float wih[4][16];
    if (!first) {
        const float* wp = Wih + (size_t)l * 4 * NODES * NODES;
        #pragma unroll
        for (int g = 0; g < 4; ++g)
            #pragma unroll
            for (int k = 0; k < 16; ++k)
                wih[g][k] = wp[(size_t)(g * NODES + j) * NODES + lane + k * 64];
    }
    float bg[4] = {0.f, 0.f, 0.f, 0.f};
    if (!first) {
        #pragma unroll
        for (int g = 0; g < 4; ++g)
            bg[g] = bih[l * 4 * NODES + g * NODES + j] + bhh[l * 4 * NODES + g * NODES + j];
    }

    u64* ring_own  = rings + (size_t)l * RING_D * NODES;
    u64* ring_prev = rings + (size_t)(l > 0 ? l - 1 : 0) * RING_D * NODES;
    u64* ring_next = rings + (size_t)(l < LAYERS - 1 ? l + 1 : l) * RING_D * NODES;

    float c = c0[l * NODES + j];
    float xpg[4] = {0.f, 0.f, 0.f, 0.f};
    if (first) {
        #pragma unroll
        for (int g = 0; g < 4; ++g) xpg[g] = XP[(size_t)0 * 4 * NODES + g * NODES + j];
    }

    for (int t = 0; t < SEQ; ++t) {
        // throttle prefetch (lane 0; normally already satisfied)
        u64 thr = 0;
        u64* tp = ring_next + (size_t)((t + 2) % RING_D) * NODES + j;
        bool do_thr = (!last) && (t >= RING_D);
        if (do_thr && lane == 0)
            thr = __hip_atomic_load(tp, __ATOMIC_RELAXED, __HIP_MEMORY_SCOPE_AGENT);

        float gate[4] = {0.f, 0.f, 0.f, 0.f};

        // ---- own-layer h(t-1) contribution ----
        if (t == 0) {
            #pragma unroll
            for (int k = 0; k < 16; ++k) {
                float h = h0[l * NODES + lane + k * 64];
                #pragma unroll
                for (int g = 0; g < 4; ++g) gate[g] += whh[g][k] * h;
            }
        } else {
            u64* so = ring_own + (size_t)(t % RING_D) * NODES;
            u64 vo[16];
            bool ok = false;
            while (!ok) {
                #pragma unroll
                for (int k = 0; k < 16; ++k)
                    vo[k] = __hip_atomic_load(&so[lane + k * 64],
                                              __ATOMIC_RELAXED, __HIP_MEMORY_SCOPE_AGENT);
                ok = true;
                #pragma unroll
                for (int k = 0; k < 16; ++k) ok = ok && ((int)(vo[k] >> 32) == t);
            }
            #pragma unroll
            for (int k = 0; k < 16; ++k) {
                float h = __uint_as_float((unsigned)vo[k]);
                #pragma unroll
                for (int g = 0; g < 4; ++g) gate[g] += whh[g][k] * h;
            }
        }

        // ---- prev-layer x(t) contribution (second group-layer only) ----
        if (!first) {
            u64* si = ring_prev + (size_t)((t + 1) % RING_D) * NODES;
            u64 vi[16];
            bool ok = false;
            while (!ok) {
                #pragma unroll
                for (int k = 0; k < 16; ++k)
                    vi[k] = __hip_atomic_load(&si[lane + k * 64],
                                              __ATOMIC_RELAXED, __HIP_MEMORY_SCOPE_AGENT);
                ok = true;
                #pragma unroll
                for (int k = 0; k < 16; ++k) ok = ok && ((int)(vi[k] >> 32) == t + 1);
            }
            #pragma unroll
            for (int k = 0; k < 16; ++k) {
                float x = __uint_as_float((unsigned)vi[k]);
                #pragma unroll
                for (int g = 0; g < 4; ++g) gate[g] += wih[g][k] * x;
            }
        }

        // ---- reduce + activations ----
        #pragma unroll
        for (int g = 0; g < 4; ++g) {
            float acc = gate[g];
            #pragma unroll
            for (int off = 32; off > 0; off >>= 1) acc += __shfl_xor(acc, off);
            gate[g] = acc + (first ? xpg[g] : bg[g]);
        }

        float ig = sigmoidf_(gate[0]);
        float fg = sigmoidf_(gate[1]);
        float gg = tanhf(gate[2]);
        float og = sigmoidf_(gate[3]);
        c = fg * c + ig * gg;
        float h = og * tanhf(c);

        if (lane == 0) {
            if (do_thr) {
                int thresh = t + 2 - RING_D;
                u64 tv = thr;
                while ((int)(tv >> 32) < thresh)
                    tv = __hip_atomic_load(tp, __ATOMIC_RELAXED, __HIP_MEMORY_SCOPE_AGENT);
            }
            u64 pv = ((u64)(unsigned)(t + 1) << 32) | (u64)__float_as_uint(h);
            __hip_atomic_store(&ring_own[(size_t)((t + 1) % RING_D) * NODES + j], pv,
                               __ATOMIC_RELAXED, __HIP_MEMORY_SCOPE_AGENT);
            if (last) Yout[(size_t)t * NODES + j] = h;
        }

        if (first) {
            int tn = (t + 1 < SEQ) ? (t + 1) : t;
            #pragma unroll
            for (int g = 0; g < 4; ++g)
                xpg[g] = XP[(size_t)tn * 4 * NODES + g * NODES + j];
        }
    }
}

// ---------------- FC2: leaky(Y) @ W2^T + b2 ----------------
__global__ __launch_bounds__(256) void fc2_kernel(
    const float* __restrict__ Y, const float* __restrict__ W2,
    const float* __restrict__ b2, float* __restrict__ out)
{
    int t = blockIdx.x;
    __shared__ float ys[NODES];
    int tid = threadIdx.x;
    for (int n = tid; n < NODES; n += 256) {
        float v = Y[(size_t)t * NODES + n];
        ys[n] = v > 0.f ? v : SLOPE * v;
    }
    __syncthreads();
    int wave = tid >> 6, lane = tid & 63;
    for (int o = wave; o < OUT_DIM; o += 4) {
        float acc = 0.f;
        const float* w = W2 + o * NODES;
        #pragma unroll
        for (int k = 0; k < 16; ++k) acc += w[lane + k * 64] * ys[lane + k * 64];
        #pragma unroll
        for (int off = 32; off > 0; off >>= 1) acc += __shfl_xor(acc, off);
        if (lane == 0) out[t * OUT_DIM + o] = acc + b2[o];
    }
}

extern "C" void kernel_launch(void* const* d_in, const int* in_sizes, int n_in,
                              void* d_out, int out_size, void* d_ws, size_t ws_size,
                              hipStream_t stream) {
    const float* sim  = (const float*)d_in[0];
    const float* relv = (const float*)d_in[1];
    const float* act  = (const float*)d_in[2];
    const float* W1   = (const float*)d_in[3];
    const float* b1   = (const float*)d_in[4];
    const float* W_ih = (const float*)d_in[5];
    const float* W_hh = (const float*)d_in[6];
    const float* b_ih = (const float*)d_in[7];
    const float* b_hh = (const float*)d_in[8];
    const float* W2   = (const float*)d_in[9];
    const float* b2   = (const float*)d_in[10];
    const float* h0   = (const float*)d_in[11];
    const float* c0   = (const float*)d_in[12];
    float* out = (float*)d_out;

    char* ws = (char*)d_ws;
    float* xbuf = (float*)ws;                                   // 8 MB (FC1 out; later Y4)
    float* xp   = (float*)(ws + (size_t)8 * 1024 * 1024);       // 32 MB (XP, reused per group)
    float* ya   = (float*)(ws + (size_t)40 * 1024 * 1024);      // 8 MB (Y1, then Y3)
    u64*   rings = (u64*)(ws + (size_t)48 * 1024 * 1024);       // 640 KB

    // zero rings in-graph every launch -> no stale flags across replays
    hipMemsetAsync(rings, 0, (size_t)LAYERS * RING_D * NODES * sizeof(u64), stream);

    fc1_kernel<<<SEQ, 256, 0, stream>>>(sim, relv, act, W1, b1, xbuf);

    // ---- group [0,1]: 256 blocks x 512 threads (<=256 coop blocks!) ----
    xproj_kernel<<<dim3(4 * NODES / BN, SEQ / BM), 256, 0, stream>>>(
        xbuf, W_ih, b_ih, b_hh, xp);
    {
        int l_base = 0, nl = 2;
        void* args[] = { (void*)&W_ih, (void*)&W_hh, (void*)&b_ih, (void*)&b_hh,
                         (void*)&xp, (void*)&h0, (void*)&c0, (void*)&ya,
                         (void*)&rings, (void*)&l_base, (void*)&nl };
        hipLaunchCooperativeKernel((const void*)lstm_group_kernel,
                                   dim3(256), dim3(512), args, 0, stream);
    }

    // ---- group [2,3] ----
    xproj_kernel<<<dim3(4 * NODES / BN, SEQ / BM), 256, 0, stream>>>(
        ya, W_ih + (size_t)2 * 4 * NODES * NODES,
        b_ih + 2 * 4 * NODES, b_hh + 2 * 4 * NODES, xp);
    {
        int l_base = 2, nl = 2;
        void* args[] = { (void*)&W_ih, (void*)&W_hh, (void*)&b_ih, (void*)&b_hh,
                         (void*)&xp, (void*)&h0, (void*)&c0, (void*)&ya,
                         (void*)&rings, (void*)&l_base, (void*)&nl };
        hipLaunchCooperativeKernel((const void*)lstm_group_kernel,
                                   dim3(256), dim3(512), args, 0, stream);
    }

    // ---- group [4] ----
    xproj_kernel<<<dim3(4 * NODES / BN, SEQ / BM), 256, 0, stream>>>(
        ya, W_ih + (size_t)4 * 4 * NODES * NODES,
        b_ih + 4 * 4 * NODES, b_hh + 4 * 4 * NODES, xp);
    {
        int l_base = 4, nl = 1;
        void* args[] = { (void*)&W_ih, (void*)&W_hh, (void*)&b_ih, (void*)&b_hh,
                         (void*)&xp, (void*)&h0, (void*)&c0, (void*)&xbuf,
                         (void*)&rings, (void*)&l_base, (void*)&nl };
        hipLaunchCooperativeKernel((const void*)lstm_group_kernel,
                                   dim3(256), dim3(256), args, 0, stream);
    }

    fc2_kernel<<<SEQ, 256, 0, stream>>>(xbuf, W2, b2, out);
}